// Round 7
// baseline (385.878 us; speedup 1.0000x reference)
//
#include <hip/hip_runtime.h>
#include <hip/hip_bf16.h>
#include <cmath>

// B=2, S=2048, E=1024, H=16, HD=64, ROT=64 (full-head RoPE)
#define SB 2048
#define EB 1024
#define NH 16
#define HD 64
#define KLOG 0.14391156831212788f  // ln(10000)/64

typedef unsigned short u16;
typedef unsigned int u32;
typedef __attribute__((ext_vector_type(8))) short short8;  // 8 bf16 (4 VGPRs)
typedef __attribute__((ext_vector_type(4))) float f32x4;

__device__ __forceinline__ u16 f2b(float x) {
  __hip_bfloat16 h = __float2bfloat16(x);
  return *reinterpret_cast<u16*>(&h);
}

// async global->LDS, 16 B per lane; LDS side is wave-uniform base + lane*16.
__device__ __forceinline__ void gl_lds16(const u16* g, u16* l) {
  __builtin_amdgcn_global_load_lds(
      (const __attribute__((address_space(1))) unsigned int*)g,
      (__attribute__((address_space(3))) unsigned int*)l, 16, 0, 0);
}

// ---------------------------------------------------------------------------
// fp32 -> bf16 convert for x, qkv_w, out_w in ONE launch.
// ---------------------------------------------------------------------------
#define CN1 (4096 * 1024 / 4)
#define CN2 (3072 * 1024 / 4)
#define CN3 (1024 * 1024 / 4)
__global__ __launch_bounds__(256) void conv_all(
    const float* __restrict__ x, const float* __restrict__ w1,
    const float* __restrict__ w2, u16* __restrict__ xb,
    u16* __restrict__ wqb, u16* __restrict__ owb) {
  int i = blockIdx.x * 256 + threadIdx.x;
  const float* src;
  u16* dst;
  int j;
  if (i < CN1) { src = x; dst = xb; j = i; }
  else if (i < CN1 + CN2) { src = w1; dst = wqb; j = i - CN1; }
  else if (i < CN1 + CN2 + CN3) { src = w2; dst = owb; j = i - CN1 - CN2; }
  else return;
  float4 v = ((const float4*)src)[j];
  ushort4 o;
  o.x = f2b(v.x); o.y = f2b(v.y); o.z = f2b(v.z); o.w = f2b(v.w);
  ((ushort4*)dst)[j] = o;
}

// ---------------------------------------------------------------------------
// Kernel 1: qkv = x @ qkv_w^T (bf16 MFMA) + bias, fused RoPE.
// q: *0.125 (exact), row-major (B,H,S,HD). k: row-major. v: TRANSPOSED
// vt[bh][d][s]. M=4096, N=3072, K=1024. 128x128 tile, BK=32.
// ---------------------------------------------------------------------------
__global__ __launch_bounds__(256) void qkv_mfma_rope(
    const u16* __restrict__ A, const u16* __restrict__ Bw,
    const float* __restrict__ bias, u16* __restrict__ qb,
    u16* __restrict__ kb, u16* __restrict__ vt) {
  __shared__ u16 As[128 * 32];   // contiguous == global order (gl_lds16)
  __shared__ u16 Bs[128 * 32];
  __shared__ float CS[128 * 32]; // RoPE table [row][pair]
  __shared__ float SN[128 * 32];

  const int t = threadIdx.x;
  const int lane = t & 63, wv = t >> 6;
  const int l15 = lane & 15, quad = lane >> 4;
  const int wm = wv >> 1, wn = wv & 1;
  const int m0 = blockIdx.x * 128;
  const int n0 = blockIdx.y * 128;

  f32x4 acc[4][4] = {};

  for (int k0 = 0; k0 < 1024; k0 += 32) {
#pragma unroll
    for (int c = 0; c < 2; c++) {
      int r = wv * 32 + c * 16;
      const u16* ga = A + (size_t)(m0 + r + (lane >> 2)) * 1024 + k0 + (lane & 3) * 8;
      const u16* gb = Bw + (size_t)(n0 + r + (lane >> 2)) * 1024 + k0 + (lane & 3) * 8;
      gl_lds16(ga, &As[r * 32]);
      gl_lds16(gb, &Bs[r * 32]);
    }
    __syncthreads();

    short8 a[4], b[4];
#pragma unroll
    for (int mi = 0; mi < 4; mi++)
      a[mi] = *(const short8*)&As[(wm * 64 + mi * 16 + l15) * 32 + quad * 8];
#pragma unroll
    for (int ni = 0; ni < 4; ni++)
      b[ni] = *(const short8*)&Bs[(wn * 64 + ni * 16 + l15) * 32 + quad * 8];
#pragma unroll
    for (int mi = 0; mi < 4; mi++)
#pragma unroll
      for (int ni = 0; ni < 4; ni++)
        acc[mi][ni] = __builtin_amdgcn_mfma_f32_16x16x32_bf16(a[mi], b[ni], acc[mi][ni], 0, 0, 0);
    __syncthreads();
  }

  const int n_base = n0 + wn * 64;
  const int which = n_base >> 10;  // 0=q 1=k 2=v (uniform per wave)
  float b4[4];
#pragma unroll
  for (int ni = 0; ni < 4; ni++) b4[ni] = bias[n_base + ni * 16 + l15];

  if (which < 2) {
#pragma unroll
    for (int i = 0; i < 16; i++) {
      int idx = t + i * 256;
      int row = idx >> 5, p = idx & 31;
      float spos = (float)((m0 & 2047) + row);
      float theta = spos * expf(-(float)(2 * p) * KLOG);
      float sn_, cs_;
      sincosf(theta, &sn_, &cs_);
      CS[idx] = cs_; SN[idx] = sn_;
    }
    __syncthreads();
  }

  const int h = (n_base & 1023) >> 6;
#pragma unroll
  for (int mi = 0; mi < 4; mi++) {
#pragma unroll
    for (int r = 0; r < 4; r++) {
      int row = wm * 64 + mi * 16 + quad * 4 + r;
      int m = m0 + row;
      int bb = m >> 11, s = m & 2047;
      if (which < 2) {
        u16* dst = (which == 0) ? qb : kb;
        size_t obase = ((size_t)(bb * NH + h) * SB + s) * HD;
#pragma unroll
        for (int ni = 0; ni < 4; ni++) {
          float v = acc[mi][ni][r] + b4[ni];
          int d = ni * 16 + l15;
          float pv = __shfl_xor(v, 1, 64);  // partner column d^1
          float c = CS[row * 32 + (d >> 1)];
          float sn_ = SN[row * 32 + (d >> 1)];
          v = v * c + pv * ((d & 1) ? sn_ : -sn_);
          if (which == 0) v *= 0.125f;  // fold softmax scale into q (exact)
          dst[obase + d] = f2b(v);
        }
      } else {
        // v: store transposed vt[bh][d][s]
        size_t tbase = (size_t)(bb * NH + h) * HD;
#pragma unroll
        for (int ni = 0; ni < 4; ni++) {
          float v = acc[mi][ni][r] + b4[ni];
          int d = ni * 16 + l15;
          vt[(tbase + d) * SB + s] = f2b(v);
        }
      }
    }
  }
}

// ---------------------------------------------------------------------------
// Kernel 2: flash attention, S^T formulation, NO LDS staging / NO barriers.
// All MFMA operands are frag-native in global memory: K rows (A-frag),
// producer-transposed V rows (A-frag), Q rows (B-frag). L1 serves the 4x
// intra-block reuse of K/V tiles, L2 the 16x cross-block (same bh) reuse.
// Only LDS use: wave-private Ps2 for the P^T C-layout -> B-frag shuffle
// (2-way bank aliasing = free; no __syncthreads anywhere).
// Block = 4 waves, q-tile 64 (wave -> 16 qrows). K-tiles of 64.
// ---------------------------------------------------------------------------
__global__ __launch_bounds__(256, 4) void attn_mfma(
    const u16* __restrict__ qb, const u16* __restrict__ kb,
    const u16* __restrict__ vt, const int* __restrict__ mask,
    u16* __restrict__ ctx) {
  __shared__ u32 Ps2[4][32][20];   // per-wave [krow-pair][qrow]

  const int bh = blockIdx.x, b = bh >> 4, h = bh & 15;
  const int q0 = blockIdx.y * 64;
  const int t = threadIdx.x;
  const int lane = t & 63, wv = t >> 6;
  const int l15 = lane & 15, quad = lane >> 4;

  // Q B-frags from global (coalesced): qrow = q0 + wv*16 + l15
  short8 bq[2];
  {
    const u16* qp = qb + ((size_t)bh * SB + q0 + wv * 16 + l15) * HD;
    bq[0] = *(const short8*)&qp[quad * 8];
    bq[1] = *(const short8*)&qp[32 + quad * 8];
  }

  const u16* kbase = kb + (size_t)bh * SB * HD;
  const u16* vbase = vt + (size_t)bh * HD * SB;
  const int* mbase = mask + b * SB;

  f32x4 o[4] = {};
  float m_i = -INFINITY, l_i = 0.f;

  for (int kt = 0; kt < SB / 64; kt++) {
    // K A-frags: rows krow = kt*64 + mb*16 + l15, 16 B per lane
    short8 ak0[4], ak1[4];
#pragma unroll
    for (int mb = 0; mb < 4; mb++) {
      const u16* kp = kbase + (size_t)(kt * 64 + mb * 16 + l15) * HD;
      ak0[mb] = *(const short8*)&kp[quad * 8];
      ak1[mb] = *(const short8*)&kp[32 + quad * 8];
    }
    // V A-frags issued now, consumed after softmax (latency hidden by exp)
    short8 av0[4], av1[4];
#pragma unroll
    for (int nb = 0; nb < 4; nb++) {
      const u16* vp = vbase + (size_t)(nb * 16 + l15) * SB + kt * 64;
      av0[nb] = *(const short8*)&vp[quad * 8];
      av1[nb] = *(const short8*)&vp[32 + quad * 8];
    }
    int mk4[4][4];
#pragma unroll
    for (int mb = 0; mb < 4; mb++) {
      int4 mv = *(const int4*)&mbase[kt * 64 + mb * 16 + quad * 4];
      mk4[mb][0] = mv.x; mk4[mb][1] = mv.y; mk4[mb][2] = mv.z; mk4[mb][3] = mv.w;
    }

    // S^T: s[mb][r] = score(krow = mb*16+quad*4+r, qrow = l15)
    f32x4 s[4] = {};
#pragma unroll
    for (int mb = 0; mb < 4; mb++) {
      s[mb] = __builtin_amdgcn_mfma_f32_16x16x32_bf16(ak0[mb], bq[0], s[mb], 0, 0, 0);
      s[mb] = __builtin_amdgcn_mfma_f32_16x16x32_bf16(ak1[mb], bq[1], s[mb], 0, 0, 0);
    }

    // online softmax (per-lane state; reduce across quads via 2 shuffles)
    float mx = -INFINITY;
#pragma unroll
    for (int mb = 0; mb < 4; mb++)
#pragma unroll
      for (int r = 0; r < 4; r++) {
        float sv = mk4[mb][r] ? s[mb][r] : -INFINITY;
        s[mb][r] = sv;
        mx = fmaxf(mx, sv);
      }
    mx = fmaxf(mx, __shfl_xor(mx, 16, 64));
    mx = fmaxf(mx, __shfl_xor(mx, 32, 64));
    float mn = fmaxf(m_i, mx);
    float mn_s = (mn == -INFINITY) ? 0.f : mn;  // avoid inf-inf
    float a = __expf(m_i - mn_s);
    float rs = 0.f;
#pragma unroll
    for (int mb = 0; mb < 4; mb++)
#pragma unroll
      for (int r = 0; r < 4; r++) {
        float p = __expf(s[mb][r] - mn_s);
        s[mb][r] = p;
        rs += p;
      }
    rs += __shfl_xor(rs, 16, 64);
    rs += __shfl_xor(rs, 32, 64);
    l_i = l_i * a + rs;
    m_i = mn;

    // P^T krow-pairs -> Ps2 (wave-private, in-pipe ordered, no barrier)
#pragma unroll
    for (int mb = 0; mb < 4; mb++)
#pragma unroll
      for (int pr = 0; pr < 2; pr++) {
        u32 pk = (u32)f2b(s[mb][2 * pr]) | ((u32)f2b(s[mb][2 * pr + 1]) << 16);
        Ps2[wv][mb * 8 + quad * 2 + pr][l15] = pk;
      }
    short8 pb[2];
#pragma unroll
    for (int kk = 0; kk < 2; kk++) {
      u32 w[4];
#pragma unroll
      for (int j = 0; j < 4; j++)
        w[j] = Ps2[wv][kk * 16 + quad * 4 + j][l15];
      pb[kk] = *(const short8*)w;
    }

    // O^T: o[nb][r] = O(d = nb*16+quad*4+r, qrow = l15)
#pragma unroll
    for (int nb = 0; nb < 4; nb++) {
#pragma unroll
      for (int r = 0; r < 4; r++) o[nb][r] *= a;
      o[nb] = __builtin_amdgcn_mfma_f32_16x16x32_bf16(av0[nb], pb[0], o[nb], 0, 0, 0);
      o[nb] = __builtin_amdgcn_mfma_f32_16x16x32_bf16(av1[nb], pb[1], o[nb], 0, 0, 0);
    }
  }

  // epilogue: ctx (B,S,E) bf16; in-lane d-pairs pack to u32 stores
  {
    float linv = 1.f / l_i;
    int qrow = q0 + wv * 16 + l15;
    size_t base = ((size_t)b * SB + qrow) * EB + h * HD;
#pragma unroll
    for (int nb = 0; nb < 4; nb++)
#pragma unroll
      for (int pr = 0; pr < 2; pr++) {
        int d = nb * 16 + quad * 4 + 2 * pr;
        u32 pk = (u32)f2b(o[nb][2 * pr] * linv) |
                 ((u32)f2b(o[nb][2 * pr + 1] * linv) << 16);
        *(u32*)&ctx[base + d] = pk;
      }
  }
}

// ---------------------------------------------------------------------------
// Kernel 3: out = ctx @ out_w^T + out_b (bf16 MFMA, fp32 out).
// M=4096, N=1024, K=1024. 128x128 tile, BK=32.
// ---------------------------------------------------------------------------
__global__ __launch_bounds__(256) void out_mfma(
    const u16* __restrict__ A, const u16* __restrict__ Bw,
    const float* __restrict__ bias, float* __restrict__ out) {
  __shared__ u16 As[128 * 32];
  __shared__ u16 Bs[128 * 32];

  const int t = threadIdx.x;
  const int lane = t & 63, wv = t >> 6;
  const int l15 = lane & 15, quad = lane >> 4;
  const int wm = wv >> 1, wn = wv & 1;
  const int m0 = blockIdx.x * 128;
  const int n0 = blockIdx.y * 128;

  f32x4 acc[4][4] = {};

  for (int k0 = 0; k0 < 1024; k0 += 32) {
#pragma unroll
    for (int c = 0; c < 2; c++) {
      int r = wv * 32 + c * 16;
      const u16* ga = A + (size_t)(m0 + r + (lane >> 2)) * 1024 + k0 + (lane & 3) * 8;
      const u16* gb = Bw + (size_t)(n0 + r + (lane >> 2)) * 1024 + k0 + (lane & 3) * 8;
      gl_lds16(ga, &As[r * 32]);
      gl_lds16(gb, &Bs[r * 32]);
    }
    __syncthreads();

    short8 a[4], b[4];
#pragma unroll
    for (int mi = 0; mi < 4; mi++)
      a[mi] = *(const short8*)&As[(wm * 64 + mi * 16 + l15) * 32 + quad * 8];
#pragma unroll
    for (int ni = 0; ni < 4; ni++)
      b[ni] = *(const short8*)&Bs[(wn * 64 + ni * 16 + l15) * 32 + quad * 8];
#pragma unroll
    for (int mi = 0; mi < 4; mi++)
#pragma unroll
      for (int ni = 0; ni < 4; ni++)
        acc[mi][ni] = __builtin_amdgcn_mfma_f32_16x16x32_bf16(a[mi], b[ni], acc[mi][ni], 0, 0, 0);
    __syncthreads();
  }

  float b4[4];
#pragma unroll
  for (int ni = 0; ni < 4; ni++) b4[ni] = bias[n0 + wn * 64 + ni * 16 + l15];
#pragma unroll
  for (int mi = 0; mi < 4; mi++)
#pragma unroll
    for (int r = 0; r < 4; r++) {
      int m = m0 + wm * 64 + mi * 16 + quad * 4 + r;
#pragma unroll
      for (int ni = 0; ni < 4; ni++)
        out[(size_t)m * 1024 + n0 + wn * 64 + ni * 16 + l15] = acc[mi][ni][r] + b4[ni];
    }
}

extern "C" void kernel_launch(void* const* d_in, const int* in_sizes, int n_in,
                              void* d_out, int out_size, void* d_ws, size_t ws_size,
                              hipStream_t stream) {
  const float* x     = (const float*)d_in[0];
  const int* mask    = (const int*)d_in[1];
  const float* qkv_w = (const float*)d_in[2];
  const float* qkv_b = (const float*)d_in[3];
  const float* out_w = (const float*)d_in[4];
  const float* out_b = (const float*)d_in[5];
  float* out = (float*)d_out;

  char* wsb = (char*)d_ws;
  u16* xb  = (u16*)wsb;                         // 8 MB  (4096x1024 bf16)
  u16* wqb = (u16*)(wsb + ( 8ull << 20));       // 6 MB  (3072x1024)
  u16* owb = (u16*)(wsb + (14ull << 20));       // 2 MB  (1024x1024)
  u16* qb  = (u16*)(wsb + (16ull << 20));       // 8 MB  (pre-scaled by 1/8)
  u16* kb  = (u16*)(wsb + (24ull << 20));       // 8 MB
  u16* vtb = (u16*)(wsb + (32ull << 20));       // 8 MB  (V transposed [bh][d][s])
  u16* cxb = (u16*)(wsb + (40ull << 20));       // 8 MB -> total 48 MB

  dim3 blk(256);
  hipLaunchKernelGGL(conv_all, dim3((CN1 + CN2 + CN3 + 255) / 256), blk, 0, stream,
                     x, qkv_w, out_w, xb, wqb, owb);

  hipLaunchKernelGGL(qkv_mfma_rope, dim3(32, 24), blk, 0, stream,
                     xb, wqb, qkv_b, qb, kb, vtb);

  hipLaunchKernelGGL(attn_mfma, dim3(32, 32), blk, 0, stream, qb, kb, vtb, mask, cxb);

  hipLaunchKernelGGL(out_mfma, dim3(32, 8), blk, 0, stream, cxb, owb, out_b, out);
}

// Round 8
// 213.620 us; speedup vs baseline: 1.8064x; 1.8064x over previous
//
#include <hip/hip_runtime.h>
#include <hip/hip_bf16.h>
#include <cmath>

// B=2, S=2048, E=1024, H=16, HD=64, ROT=64 (full-head RoPE)
#define SB 2048
#define EB 1024
#define NH 16
#define HD 64
#define KLOG 0.14391156831212788f  // ln(10000)/64

typedef unsigned short u16;
typedef unsigned int u32;
typedef __attribute__((ext_vector_type(8))) short short8;  // 8 bf16 (4 VGPRs)
typedef __attribute__((ext_vector_type(4))) float f32x4;

__device__ __forceinline__ u16 f2b(float x) {
  __hip_bfloat16 h = __float2bfloat16(x);
  return *reinterpret_cast<u16*>(&h);
}

// async global->LDS, 16 B per lane; LDS side is wave-uniform base + lane*16.
__device__ __forceinline__ void gl_lds16(const u16* g, u16* l) {
  __builtin_amdgcn_global_load_lds(
      (const __attribute__((address_space(1))) unsigned int*)g,
      (__attribute__((address_space(3))) unsigned int*)l, 16, 0, 0);
}

// ---------------------------------------------------------------------------
// fp32 -> bf16 convert for x, qkv_w, out_w in ONE launch.
// ---------------------------------------------------------------------------
#define CN1 (4096 * 1024 / 4)
#define CN2 (3072 * 1024 / 4)
#define CN3 (1024 * 1024 / 4)
__global__ __launch_bounds__(256) void conv_all(
    const float* __restrict__ x, const float* __restrict__ w1,
    const float* __restrict__ w2, u16* __restrict__ xb,
    u16* __restrict__ wqb, u16* __restrict__ owb) {
  int i = blockIdx.x * 256 + threadIdx.x;
  const float* src;
  u16* dst;
  int j;
  if (i < CN1) { src = x; dst = xb; j = i; }
  else if (i < CN1 + CN2) { src = w1; dst = wqb; j = i - CN1; }
  else if (i < CN1 + CN2 + CN3) { src = w2; dst = owb; j = i - CN1 - CN2; }
  else return;
  float4 v = ((const float4*)src)[j];
  ushort4 o;
  o.x = f2b(v.x); o.y = f2b(v.y); o.z = f2b(v.z); o.w = f2b(v.w);
  ((ushort4*)dst)[j] = o;
}

// ---------------------------------------------------------------------------
// Kernel 1: qkv = x @ qkv_w^T (bf16 MFMA) + bias, fused RoPE.
// q: *0.125 (exact), row-major (B,H,S,HD). k: row-major. v: TRANSPOSED
// vt[bh][d][s]. M=4096, N=3072, K=1024. 128x128 tile, BK=32.
// ---------------------------------------------------------------------------
__global__ __launch_bounds__(256) void qkv_mfma_rope(
    const u16* __restrict__ A, const u16* __restrict__ Bw,
    const float* __restrict__ bias, u16* __restrict__ qb,
    u16* __restrict__ kb, u16* __restrict__ vt) {
  __shared__ u16 As[128 * 32];   // contiguous == global order (gl_lds16)
  __shared__ u16 Bs[128 * 32];
  __shared__ float CS[128 * 32]; // RoPE table [row][pair]
  __shared__ float SN[128 * 32];

  const int t = threadIdx.x;
  const int lane = t & 63, wv = t >> 6;
  const int l15 = lane & 15, quad = lane >> 4;
  const int wm = wv >> 1, wn = wv & 1;
  const int m0 = blockIdx.x * 128;
  const int n0 = blockIdx.y * 128;

  f32x4 acc[4][4] = {};

  for (int k0 = 0; k0 < 1024; k0 += 32) {
#pragma unroll
    for (int c = 0; c < 2; c++) {
      int r = wv * 32 + c * 16;
      const u16* ga = A + (size_t)(m0 + r + (lane >> 2)) * 1024 + k0 + (lane & 3) * 8;
      const u16* gb = Bw + (size_t)(n0 + r + (lane >> 2)) * 1024 + k0 + (lane & 3) * 8;
      gl_lds16(ga, &As[r * 32]);
      gl_lds16(gb, &Bs[r * 32]);
    }
    __syncthreads();

    short8 a[4], b[4];
#pragma unroll
    for (int mi = 0; mi < 4; mi++)
      a[mi] = *(const short8*)&As[(wm * 64 + mi * 16 + l15) * 32 + quad * 8];
#pragma unroll
    for (int ni = 0; ni < 4; ni++)
      b[ni] = *(const short8*)&Bs[(wn * 64 + ni * 16 + l15) * 32 + quad * 8];
#pragma unroll
    for (int mi = 0; mi < 4; mi++)
#pragma unroll
      for (int ni = 0; ni < 4; ni++)
        acc[mi][ni] = __builtin_amdgcn_mfma_f32_16x16x32_bf16(a[mi], b[ni], acc[mi][ni], 0, 0, 0);
    __syncthreads();
  }

  const int n_base = n0 + wn * 64;
  const int which = n_base >> 10;  // 0=q 1=k 2=v (uniform per wave)
  float b4[4];
#pragma unroll
  for (int ni = 0; ni < 4; ni++) b4[ni] = bias[n_base + ni * 16 + l15];

  if (which < 2) {
#pragma unroll
    for (int i = 0; i < 16; i++) {
      int idx = t + i * 256;
      int row = idx >> 5, p = idx & 31;
      float spos = (float)((m0 & 2047) + row);
      float theta = spos * expf(-(float)(2 * p) * KLOG);
      float sn_, cs_;
      sincosf(theta, &sn_, &cs_);
      CS[idx] = cs_; SN[idx] = sn_;
    }
    __syncthreads();
  }

  const int h = (n_base & 1023) >> 6;
#pragma unroll
  for (int mi = 0; mi < 4; mi++) {
#pragma unroll
    for (int r = 0; r < 4; r++) {
      int row = wm * 64 + mi * 16 + quad * 4 + r;
      int m = m0 + row;
      int bb = m >> 11, s = m & 2047;
      if (which < 2) {
        u16* dst = (which == 0) ? qb : kb;
        size_t obase = ((size_t)(bb * NH + h) * SB + s) * HD;
#pragma unroll
        for (int ni = 0; ni < 4; ni++) {
          float v = acc[mi][ni][r] + b4[ni];
          int d = ni * 16 + l15;
          float pv = __shfl_xor(v, 1, 64);  // partner column d^1
          float c = CS[row * 32 + (d >> 1)];
          float sn_ = SN[row * 32 + (d >> 1)];
          v = v * c + pv * ((d & 1) ? sn_ : -sn_);
          if (which == 0) v *= 0.125f;  // fold softmax scale into q (exact)
          dst[obase + d] = f2b(v);
        }
      } else {
        // v: store transposed vt[bh][d][s]
        size_t tbase = (size_t)(bb * NH + h) * HD;
#pragma unroll
        for (int ni = 0; ni < 4; ni++) {
          float v = acc[mi][ni][r] + b4[ni];
          int d = ni * 16 + l15;
          vt[(tbase + d) * SB + s] = f2b(v);
        }
      }
    }
  }
}

// ---------------------------------------------------------------------------
// Kernel 2: flash attention, S^T formulation. 8 waves (512 thr), q-tile 128
// (wave -> 16 qrows). K-tiles of 64, DOUBLE-BUFFERED in LDS: one barrier per
// tile; each thread prefetches its single uint4 of K and V for kt+1 right
// after the barrier, overlapping compute(kt) (8 VGPRs of held state only).
// S^T = mfma(A=K, B=Q): krow in-lane, qrow = l15. One (m,l) per lane.
// P^T pairs -> wave-private Ps2 (no barrier); O^T = mfma(A=Vt, B=P).
// ---------------------------------------------------------------------------
__global__ __launch_bounds__(512, 4) void attn_mfma(
    const u16* __restrict__ qb, const u16* __restrict__ kb,
    const u16* __restrict__ vt, const int* __restrict__ mask,
    u16* __restrict__ ctx) {
  __shared__ u16 Ks[2][64][72];    // [buf][krow][d]
  __shared__ u16 Vt[2][64][72];    // [buf][d][krow]
  __shared__ u32 Ps2[8][32][20];   // per-wave [krow-pair][qrow]
  __shared__ int mks[2][64];

  const int bh = blockIdx.x, b = bh >> 4, h = bh & 15;
  const int q0 = blockIdx.y * 128;
  const int t = threadIdx.x;
  const int lane = t & 63, wv = t >> 6;   // wv 0..7
  const int l15 = lane & 15, quad = lane >> 4;

  // Q B-frags from global (coalesced): qrow = q0 + wv*16 + l15
  short8 bq[2];
  {
    const u16* qp = qb + ((size_t)bh * SB + q0 + wv * 16 + l15) * HD;
    bq[0] = *(const short8*)&qp[quad * 8];
    bq[1] = *(const short8*)&qp[32 + quad * 8];
  }

  const u16* kbase = kb + (size_t)bh * SB * HD;
  const u16* vbase = vt + (size_t)bh * HD * SB;
  const int* mbase = mask + b * SB;

  // staging coords: each of 512 threads owns one 16B chunk of K and V tile
  const int sr = t >> 3, sc = t & 7;   // row 0..63, 16B-chunk 0..7

  uint4 kreg = *(const uint4*)&kbase[(size_t)sr * HD + sc * 8];
  uint4 vreg = *(const uint4*)&vbase[(size_t)sr * SB + sc * 8];
  int mreg = (t < 64) ? mbase[t] : 0;

  f32x4 o[4] = {};
  float m_i = -INFINITY, l_i = 0.f;

  for (int kt = 0; kt < SB / 64; kt++) {
    const int bufi = kt & 1;
    *(uint4*)&Ks[bufi][sr][sc * 8] = kreg;
    *(uint4*)&Vt[bufi][sr][sc * 8] = vreg;
    if (t < 64) mks[bufi][t] = mreg;
    __syncthreads();  // buf ready (single barrier per tile; dbuf makes it safe)

    // prefetch kt+1 (overlaps compute below; drained at next barrier)
    if (kt + 1 < SB / 64) {
      kreg = *(const uint4*)&kbase[(size_t)((kt + 1) * 64 + sr) * HD + sc * 8];
      vreg = *(const uint4*)&vbase[(size_t)sr * SB + (kt + 1) * 64 + sc * 8];
      if (t < 64) mreg = mbase[(kt + 1) * 64 + t];
    }

    // S^T: s[mb][r] = score(krow = mb*16+quad*4+r, qrow = l15)
    f32x4 s[4] = {};
#pragma unroll
    for (int mb = 0; mb < 4; mb++) {
      short8 a0 = *(const short8*)&Ks[bufi][mb * 16 + l15][quad * 8];
      short8 a1 = *(const short8*)&Ks[bufi][mb * 16 + l15][32 + quad * 8];
      s[mb] = __builtin_amdgcn_mfma_f32_16x16x32_bf16(a0, bq[0], s[mb], 0, 0, 0);
      s[mb] = __builtin_amdgcn_mfma_f32_16x16x32_bf16(a1, bq[1], s[mb], 0, 0, 0);
    }

    // online softmax (per-lane state; reduce across quads via 2 shuffles)
    float mx = -INFINITY;
#pragma unroll
    for (int mb = 0; mb < 4; mb++) {
      int4 mv = *(const int4*)&mks[bufi][mb * 16 + quad * 4];
      int mk4[4] = {mv.x, mv.y, mv.z, mv.w};
#pragma unroll
      for (int r = 0; r < 4; r++) {
        float sv = mk4[r] ? s[mb][r] : -INFINITY;
        s[mb][r] = sv;
        mx = fmaxf(mx, sv);
      }
    }
    mx = fmaxf(mx, __shfl_xor(mx, 16, 64));
    mx = fmaxf(mx, __shfl_xor(mx, 32, 64));
    float mn = fmaxf(m_i, mx);
    float mn_s = (mn == -INFINITY) ? 0.f : mn;  // avoid inf-inf
    float a = __expf(m_i - mn_s);
    float rs = 0.f;
#pragma unroll
    for (int mb = 0; mb < 4; mb++)
#pragma unroll
      for (int r = 0; r < 4; r++) {
        float p = __expf(s[mb][r] - mn_s);
        s[mb][r] = p;
        rs += p;
      }
    rs += __shfl_xor(rs, 16, 64);
    rs += __shfl_xor(rs, 32, 64);
    l_i = l_i * a + rs;
    m_i = mn;

    // P^T krow-pairs -> Ps2 (wave-private, in-pipe ordered, no barrier)
#pragma unroll
    for (int mb = 0; mb < 4; mb++)
#pragma unroll
      for (int pr = 0; pr < 2; pr++) {
        u32 pk = (u32)f2b(s[mb][2 * pr]) | ((u32)f2b(s[mb][2 * pr + 1]) << 16);
        Ps2[wv][mb * 8 + quad * 2 + pr][l15] = pk;
      }
    short8 pb[2];
#pragma unroll
    for (int kk = 0; kk < 2; kk++) {
      u32 w[4];
#pragma unroll
      for (int j = 0; j < 4; j++)
        w[j] = Ps2[wv][kk * 16 + quad * 4 + j][l15];
      pb[kk] = *(const short8*)w;
    }

    // O^T: o[nb][r] = O(d = nb*16+quad*4+r, qrow = l15)
#pragma unroll
    for (int nb = 0; nb < 4; nb++) {
      short8 v0 = *(const short8*)&Vt[bufi][nb * 16 + l15][quad * 8];
      short8 v1 = *(const short8*)&Vt[bufi][nb * 16 + l15][32 + quad * 8];
#pragma unroll
      for (int r = 0; r < 4; r++) o[nb][r] *= a;
      o[nb] = __builtin_amdgcn_mfma_f32_16x16x32_bf16(v0, pb[0], o[nb], 0, 0, 0);
      o[nb] = __builtin_amdgcn_mfma_f32_16x16x32_bf16(v1, pb[1], o[nb], 0, 0, 0);
    }
  }

  // epilogue: ctx (B,S,E) bf16; in-lane d-pairs pack to u32 stores
  {
    float linv = 1.f / l_i;
    int qrow = q0 + wv * 16 + l15;
    size_t base = ((size_t)b * SB + qrow) * EB + h * HD;
#pragma unroll
    for (int nb = 0; nb < 4; nb++)
#pragma unroll
      for (int pr = 0; pr < 2; pr++) {
        int d = nb * 16 + quad * 4 + 2 * pr;
        u32 pk = (u32)f2b(o[nb][2 * pr] * linv) |
                 ((u32)f2b(o[nb][2 * pr + 1] * linv) << 16);
        *(u32*)&ctx[base + d] = pk;
      }
  }
}

// ---------------------------------------------------------------------------
// Kernel 3: out = ctx @ out_w^T + out_b (bf16 MFMA, fp32 out).
// M=4096, N=1024, K=1024. 128x128 tile, BK=32.
// ---------------------------------------------------------------------------
__global__ __launch_bounds__(256) void out_mfma(
    const u16* __restrict__ A, const u16* __restrict__ Bw,
    const float* __restrict__ bias, float* __restrict__ out) {
  __shared__ u16 As[128 * 32];
  __shared__ u16 Bs[128 * 32];

  const int t = threadIdx.x;
  const int lane = t & 63, wv = t >> 6;
  const int l15 = lane & 15, quad = lane >> 4;
  const int wm = wv >> 1, wn = wv & 1;
  const int m0 = blockIdx.x * 128;
  const int n0 = blockIdx.y * 128;

  f32x4 acc[4][4] = {};

  for (int k0 = 0; k0 < 1024; k0 += 32) {
#pragma unroll
    for (int c = 0; c < 2; c++) {
      int r = wv * 32 + c * 16;
      const u16* ga = A + (size_t)(m0 + r + (lane >> 2)) * 1024 + k0 + (lane & 3) * 8;
      const u16* gb = Bw + (size_t)(n0 + r + (lane >> 2)) * 1024 + k0 + (lane & 3) * 8;
      gl_lds16(ga, &As[r * 32]);
      gl_lds16(gb, &Bs[r * 32]);
    }
    __syncthreads();

    short8 a[4], b[4];
#pragma unroll
    for (int mi = 0; mi < 4; mi++)
      a[mi] = *(const short8*)&As[(wm * 64 + mi * 16 + l15) * 32 + quad * 8];
#pragma unroll
    for (int ni = 0; ni < 4; ni++)
      b[ni] = *(const short8*)&Bs[(wn * 64 + ni * 16 + l15) * 32 + quad * 8];
#pragma unroll
    for (int mi = 0; mi < 4; mi++)
#pragma unroll
      for (int ni = 0; ni < 4; ni++)
        acc[mi][ni] = __builtin_amdgcn_mfma_f32_16x16x32_bf16(a[mi], b[ni], acc[mi][ni], 0, 0, 0);
    __syncthreads();
  }

  float b4[4];
#pragma unroll
  for (int ni = 0; ni < 4; ni++) b4[ni] = bias[n0 + wn * 64 + ni * 16 + l15];
#pragma unroll
  for (int mi = 0; mi < 4; mi++)
#pragma unroll
    for (int r = 0; r < 4; r++) {
      int m = m0 + wm * 64 + mi * 16 + quad * 4 + r;
#pragma unroll
      for (int ni = 0; ni < 4; ni++)
        out[(size_t)m * 1024 + n0 + wn * 64 + ni * 16 + l15] = acc[mi][ni][r] + b4[ni];
    }
}

extern "C" void kernel_launch(void* const* d_in, const int* in_sizes, int n_in,
                              void* d_out, int out_size, void* d_ws, size_t ws_size,
                              hipStream_t stream) {
  const float* x     = (const float*)d_in[0];
  const int* mask    = (const int*)d_in[1];
  const float* qkv_w = (const float*)d_in[2];
  const float* qkv_b = (const float*)d_in[3];
  const float* out_w = (const float*)d_in[4];
  const float* out_b = (const float*)d_in[5];
  float* out = (float*)d_out;

  char* wsb = (char*)d_ws;
  u16* xb  = (u16*)wsb;                         // 8 MB  (4096x1024 bf16)
  u16* wqb = (u16*)(wsb + ( 8ull << 20));       // 6 MB  (3072x1024)
  u16* owb = (u16*)(wsb + (14ull << 20));       // 2 MB  (1024x1024)
  u16* qb  = (u16*)(wsb + (16ull << 20));       // 8 MB  (pre-scaled by 1/8)
  u16* kb  = (u16*)(wsb + (24ull << 20));       // 8 MB
  u16* vtb = (u16*)(wsb + (32ull << 20));       // 8 MB  (V transposed [bh][d][s])
  u16* cxb = (u16*)(wsb + (40ull << 20));       // 8 MB -> total 48 MB

  dim3 blk(256);
  hipLaunchKernelGGL(conv_all, dim3((CN1 + CN2 + CN3 + 255) / 256), blk, 0, stream,
                     x, qkv_w, out_w, xb, wqb, owb);

  hipLaunchKernelGGL(qkv_mfma_rope, dim3(32, 24), blk, 0, stream,
                     xb, wqb, qkv_b, qb, kb, vtb);

  hipLaunchKernelGGL(attn_mfma, dim3(32, 16), dim3(512), 0, stream,
                     qb, kb, vtb, mask, cxb);

  hipLaunchKernelGGL(out_mfma, dim3(32, 8), blk, 0, stream, cxb, owb, out_b, out);
}